// Round 9
// baseline (57.797 us; speedup 1.0000x reference)
//
#include <hip/hip_runtime.h>

#define NT 1024
#define NS 2048
#define NH 32

typedef float f32x4 __attribute__((ext_vector_type(4)));

// One thread per (s, h). 32-lane half-wave per site s:
//   - state role: lane = h (S, H in registers)
//   - load role:  lane = time-offset within a 32-step chunk (full-wave acos prep)
// Per-step h-sum: DPP tree (row_shr 1/2/4/8 + row_bcast15 row_mask 0xa) ->
// totals at lanes 31/63; collected via DPP wave_rol1 rotate + cndmask insert
// (verified correct in R7). No ytmp LDS.
// R9: the 32 stage reads are VOLATILE INLINE-ASM ds_read_b128 -> the compiler
// MUST materialize x[32] in 128 VGPRs (asm outputs can't be rematerialized or
// sunk), one s_waitcnt lgkmcnt(0) + sched_barrier after (guide rule #18).
// Step loop is then provably pure VALU.
__global__ __launch_bounds__(256, 1)
void waternet_kernel(const float* __restrict__ P,
                     const float* __restrict__ T1,
                     const float* __restrict__ T2,
                     const float* __restrict__ E,
                     const float* __restrict__ w,
                     float* __restrict__ Y)
{
    const int tid  = threadIdx.x;
    const int lane = tid & 31;   // h index AND time-offset for loads
    const int grp  = tid >> 5;   // s-group within block (0..7)

    // XCD-contiguous s mapping (round-robin dispatch: bid%8 = XCD)
    const int bid    = blockIdx.x;
    const int sChunk = (bid & 7) * 32 + (bid >> 3);   // bijective [0,256)
    const int s      = sChunk * 8 + grp;              // [0, 2048)

    // ---- per-h gate weights (one-time) ----
    const float wm = w[lane];
    const float we = w[NH + lane];
    const float wo = w[2 * NH + lane];
    const float wa = w[3 * NH + lane];

    const float gm = expf(wm) + 1.0f;
    const float ge = 1.0f / (1.0f + expf(-we));
    const float go = 1.0f / (1.0f + expf(-wo));

    float mx = wa;
    #pragma unroll
    for (int o = 16; o; o >>= 1) mx = fmaxf(mx, __shfl_xor(mx, o));
    float ea = expf(wa - mx);
    float ssum = ea;
    #pragma unroll
    for (int o = 16; o; o >>= 1) ssum += __shfl_xor(ssum, o);
    const float ga  = ea / ssum;
    const float go1 = 1.0f - go;   // H' = h3*(1-go)
    const float gq  = go * ga;     // y-contrib = h3*go*ga

    float S  = 0.0f;
    float Hs = 0.0f;

    __shared__ f32x4 stage[8][32];   // SINGLE-buffered chunk inputs {TaP, Ps, Pl, E}

    // LDS byte offset of this group's stage row (low 32 bits of the generic
    // address of a __shared__ object = LDS offset; aperture lives in the high half)
    const unsigned lds_base = (unsigned)(size_t)&stage[grp][0];

    // lane-transposed global loads: lane l covers time row (chunk*32 + l)
    size_t base = (size_t)lane * NS + s;
    float p0 = P[base], a0 = T1[base], b0 = T2[base], e0 = E[base];
    size_t bn = base + (size_t)32 * NS;
    float pg = P[bn], ag = T1[bn], bg = T2[bn], eg = E[bn];   // chunk 1

    auto prep = [&](float p, float ta, float tb, float ee) {
        float sum   = ta + tb;                       // 2*Ta
        float ratio = sum / (tb - ta);               // tb>ta guaranteed
        ratio = fminf(fmaxf(ratio, -1.0f), 1.0f);
        float rP = 1.0f - acosf(ratio) * (1.0f / 3.1415f);
        if (ta >= 0.0f) rP = 1.0f;
        if (tb <= 0.0f) rP = 0.0f;
        float Pl  = rP * p;
        float Ps  = p - Pl;                          // (1-rP)*P
        float TaP = fmaxf(sum * 0.5f, 0.0f);         // gm>0: max(Ta*gm,0)=TaP*gm
        f32x4 v; v.x = TaP; v.y = Ps; v.z = Pl; v.w = ee;
        stage[grp][lane] = v;
    };

    prep(p0, a0, b0, e0);   // chunk 0 into stage

    const bool isLast = (lane == 31);   // hw lanes 31 and 63

    #pragma unroll 1
    for (int c = 0; c < 32; ++c) {
        // ---- forced bulk broadcast-read into 128 VGPRs (volatile asm) ----
        f32x4 x[32];
        #pragma unroll
        for (int j = 0; j < 32; ++j) {
            asm volatile("ds_read_b128 %0, %1"
                         : "=v"(x[j])
                         : "v"(lds_base + (unsigned)(j * 16))
                         : "memory");
        }
        asm volatile("s_waitcnt lgkmcnt(0)" ::: "memory");
        __builtin_amdgcn_sched_barrier(0);   // rule #18: no hoist past the wait

        // ---- prep chunk c+1: overwrites stage (DS in-order per wave; next
        //      iteration's volatile reads stay behind these writes) ----
        if (c < 31) prep(pg, ag, bg, eg);
        if (c < 30) {                                 // globals two chunks ahead
            size_t nb = base + (size_t)(c + 2) * 32 * NS;
            pg = P[nb]; ag = T1[nb]; bg = T2[nb]; eg = E[nb];
        }

        // ---- 32 pure-VALU steps; DPP tree + rotate-insert collector ----
        float acc = 0.0f;
        #pragma unroll
        for (int k = 0; k < 32; ++k) {
            const f32x4 xx = x[k];
            const float bm = xx.x * gm;                    // off-chain
            const float pw = fmaf(-xx.w, ge, xx.z);        // Pl - E*ge, off-chain
            const float Sm = fminf(S, bm);
            const float Sp = S + xx.y;                     // parallel to Sm
            const float h3 = fmaxf(Hs + (pw + Sm), 0.0f);
            S  = Sp - Sm;
            Hs = h3 * go1;
            float y = h3 * gq;

            // 32-lane sum within each half (VALU DPP, verified R7):
            {
                int t;
                t = __builtin_amdgcn_update_dpp(0, __float_as_int(y), 0x111, 0xf, 0xf, false);
                y += __int_as_float(t);   // row_shr:1
                t = __builtin_amdgcn_update_dpp(0, __float_as_int(y), 0x112, 0xf, 0xf, false);
                y += __int_as_float(t);   // row_shr:2
                t = __builtin_amdgcn_update_dpp(0, __float_as_int(y), 0x114, 0xf, 0xf, false);
                y += __int_as_float(t);   // row_shr:4
                t = __builtin_amdgcn_update_dpp(0, __float_as_int(y), 0x118, 0xf, 0xf, false);
                y += __int_as_float(t);   // row_shr:8 -> lanes 15/31/47/63 = row sums
                t = __builtin_amdgcn_update_dpp(0, __float_as_int(y), 0x142, 0xa, 0xf, false);
                y += __int_as_float(t);   // bcast15 into rows 1,3 -> lanes 31/63 = totals
            }

            // rotate-insert: step k's total lands at lane k (site A) / 32+k (B)
            int rolled = __builtin_amdgcn_update_dpp(0, __float_as_int(acc), 0x134, 0xf, 0xf, false);
            acc = isLast ? y : __int_as_float(rolled);
        }

        // lane l holds y(t = c*32 + l) for its own site
        Y[(size_t)(c * 32 + lane) * NS + s] = acc;
    }
}

extern "C" void kernel_launch(void* const* d_in, const int* in_sizes, int n_in,
                              void* d_out, int out_size, void* d_ws, size_t ws_size,
                              hipStream_t stream) {
    const float* P  = (const float*)d_in[0];
    const float* T1 = (const float*)d_in[1];
    const float* T2 = (const float*)d_in[2];
    const float* E  = (const float*)d_in[3];
    const float* w  = (const float*)d_in[4];
    float* Y = (float*)d_out;

    waternet_kernel<<<dim3(256), dim3(256), 0, stream>>>(P, T1, T2, E, w, Y);
}

// Round 10
// 50.580 us; speedup vs baseline: 1.1427x; 1.1427x over previous
//
#include <hip/hip_runtime.h>

#define NT 1024
#define NS 2048
#define NH 32

typedef float f32x4 __attribute__((ext_vector_type(4)));

// One thread per (s, h). 32-lane half-wave per site s:
//   - state role: lane = h (S, H in registers)
//   - load role:  lane = time-offset within a 32-step chunk (full-wave acos prep)
// R10: NO per-step cross-lane ops. Lane h writes its step-k contribution to
// register ycon[k]; at chunk end a 5-stage butterfly transpose-reduce
// (shfl_xor 16/8/4/2/1, 31 exchanges) leaves y(t=c*32+lane) in each lane ->
// one store per lane per chunk. Step loop is 10 pure-VALU ops, chain ~12 cyc.
// x[32] chunk inputs are forced into registers via volatile inline-asm
// ds_read_b128 (R9 mechanism, verified) + one lgkmcnt(0) + sched_barrier.
__global__ __launch_bounds__(256, 1)
void waternet_kernel(const float* __restrict__ P,
                     const float* __restrict__ T1,
                     const float* __restrict__ T2,
                     const float* __restrict__ E,
                     const float* __restrict__ w,
                     float* __restrict__ Y)
{
    const int tid  = threadIdx.x;
    const int lane = tid & 31;   // h index AND time-offset for loads
    const int grp  = tid >> 5;   // s-group within block (0..7)

    // XCD-contiguous s mapping (round-robin dispatch: bid%8 = XCD)
    const int bid    = blockIdx.x;
    const int sChunk = (bid & 7) * 32 + (bid >> 3);   // bijective [0,256)
    const int s      = sChunk * 8 + grp;              // [0, 2048)

    // ---- per-h gate weights (one-time) ----
    const float wm = w[lane];
    const float we = w[NH + lane];
    const float wo = w[2 * NH + lane];
    const float wa = w[3 * NH + lane];

    const float gm = expf(wm) + 1.0f;
    const float ge = 1.0f / (1.0f + expf(-we));
    const float go = 1.0f / (1.0f + expf(-wo));

    float mx = wa;
    #pragma unroll
    for (int o = 16; o; o >>= 1) mx = fmaxf(mx, __shfl_xor(mx, o));
    float ea = expf(wa - mx);
    float ssum = ea;
    #pragma unroll
    for (int o = 16; o; o >>= 1) ssum += __shfl_xor(ssum, o);
    const float ga  = ea / ssum;
    const float go1 = 1.0f - go;   // H' = h3*(1-go)
    const float gq  = go * ga;     // y-contrib = h3*go*ga

    float S  = 0.0f;
    float Hs = 0.0f;

    __shared__ f32x4 stage[8][32];   // SINGLE-buffered chunk inputs {TaP, Ps, Pl, E}

    // LDS byte offset of this group's stage row
    const unsigned lds_base = (unsigned)(size_t)&stage[grp][0];

    // lane-transposed global loads: lane l covers time row (chunk*32 + l)
    size_t base = (size_t)lane * NS + s;
    float p0 = P[base], a0 = T1[base], b0 = T2[base], e0 = E[base];
    size_t bn = base + (size_t)32 * NS;
    float pg = P[bn], ag = T1[bn], bg = T2[bn], eg = E[bn];   // chunk 1

    auto prep = [&](float p, float ta, float tb, float ee) {
        float sum   = ta + tb;                       // 2*Ta
        float ratio = sum / (tb - ta);               // tb>ta guaranteed
        ratio = fminf(fmaxf(ratio, -1.0f), 1.0f);
        float rP = 1.0f - acosf(ratio) * (1.0f / 3.1415f);
        if (ta >= 0.0f) rP = 1.0f;
        if (tb <= 0.0f) rP = 0.0f;
        float Pl  = rP * p;
        float Ps  = p - Pl;                          // (1-rP)*P
        float TaP = fmaxf(sum * 0.5f, 0.0f);         // gm>0: max(Ta*gm,0)=TaP*gm
        f32x4 v; v.x = TaP; v.y = Ps; v.z = Pl; v.w = ee;
        stage[grp][lane] = v;
    };

    prep(p0, a0, b0, e0);   // chunk 0 into stage

    #pragma unroll 1
    for (int c = 0; c < 32; ++c) {
        // ---- forced bulk broadcast-read into registers (volatile asm) ----
        f32x4 x[32];
        #pragma unroll
        for (int j = 0; j < 32; ++j) {
            asm volatile("ds_read_b128 %0, %1"
                         : "=v"(x[j])
                         : "v"(lds_base + (unsigned)(j * 16))
                         : "memory");
        }
        asm volatile("s_waitcnt lgkmcnt(0)" ::: "memory");
        __builtin_amdgcn_sched_barrier(0);   // rule #18: no hoist past the wait

        // ---- prep chunk c+1: overwrites stage (wave-private, DS in-order) ----
        if (c < 31) prep(pg, ag, bg, eg);
        if (c < 30) {                                 // globals two chunks ahead
            size_t nb = base + (size_t)(c + 2) * 32 * NS;
            pg = P[nb]; ag = T1[nb]; bg = T2[nb]; eg = E[nb];
        }

        // ---- 32 pure-VALU steps; contributions go to registers ----
        float ycon[32];
        #pragma unroll
        for (int k = 0; k < 32; ++k) {
            const f32x4 xx = x[k];
            const float bm = xx.x * gm;                    // off-chain
            const float pw = fmaf(-xx.w, ge, xx.z);        // Pl - E*ge, off-chain
            const float Sm = fminf(S, bm);
            const float Sp = S + xx.y;                     // parallel to Sm
            const float h3 = fmaxf(Hs + (pw + Sm), 0.0f);
            S  = Sp - Sm;
            Hs = h3 * go1;
            ycon[k] = h3 * gq;                             // register, no cross-lane
        }

        // ---- butterfly transpose-reduce over the 32-lane half ----
        // After stage o: slots halve; lane keeps slots matching its bit-o.
        // End: ycon[0] = sum over h of contrib[h][lane] = y(t = c*32 + lane).
        #pragma unroll
        for (int o = 16; o >= 1; o >>= 1) {
            #pragma unroll
            for (int j = 0; j < 16; ++j) {
                if (j < o) {   // static after unroll: j in [0, o)
                    const float lo = ycon[j];
                    const float hi = ycon[j + o];
                    const float send = (lane & o) ? lo : hi;
                    const float keep = (lane & o) ? hi : lo;
                    ycon[j] = keep + __shfl_xor(send, o);
                }
            }
        }

        // lane l holds y(t = c*32 + l) for its own site
        Y[(size_t)(c * 32 + lane) * NS + s] = ycon[0];
    }
}

extern "C" void kernel_launch(void* const* d_in, const int* in_sizes, int n_in,
                              void* d_out, int out_size, void* d_ws, size_t ws_size,
                              hipStream_t stream) {
    const float* P  = (const float*)d_in[0];
    const float* T1 = (const float*)d_in[1];
    const float* T2 = (const float*)d_in[2];
    const float* E  = (const float*)d_in[3];
    const float* w  = (const float*)d_in[4];
    float* Y = (float*)d_out;

    waternet_kernel<<<dim3(256), dim3(256), 0, stream>>>(P, T1, T2, E, w, Y);
}